// Round 4
// baseline (76.585 us; speedup 1.0000x reference)
//
#include <hip/hip_runtime.h>
#include <math.h>

#define B_ 4
#define T_ 512
#define D_ 2048
#define H_ 1024
#define E_ 2
#define NBLK 512
#define NTHR 256

#define LD4(p) (*reinterpret_cast<const float4*>(p))

__device__ __forceinline__ float waveReduceSum(float v) {
    #pragma unroll
    for (int o = 32; o > 0; o >>= 1) v += __shfl_down(v, o, 64);
    return v;
}

// Device-scope (cross-XCD-coherent) point ops — sc1 path, NO buffer_wbl2/buffer_inv.
__device__ __forceinline__ void agentStore(float* p, float v) {
    __hip_atomic_store(p, v, __ATOMIC_RELAXED, __HIP_MEMORY_SCOPE_AGENT);
}
__device__ __forceinline__ float agentLoad(const float* p) {
    return __hip_atomic_load(p, __ATOMIC_RELAXED, __HIP_MEMORY_SCOPE_AGENT);
}

// Fence-free grid barrier: __syncthreads drains each wave's vmcnt (sc1 stores
// reach the coherent point) before thread0's relaxed arrival atomic; spin on a
// relaxed agent load. No cache-maintenance instructions anywhere.
__device__ __forceinline__ void gridBarrier(int* ctr) {
    __syncthreads();
    if (threadIdx.x == 0) {
        __hip_atomic_fetch_add(ctr, 1, __ATOMIC_RELAXED, __HIP_MEMORY_SCOPE_AGENT);
        while (__hip_atomic_load(ctr, __ATOMIC_RELAXED, __HIP_MEMORY_SCOPE_AGENT) < NBLK)
            __builtin_amdgcn_s_sleep(1);
    }
    __syncthreads();
}

__global__ __launch_bounds__(NTHR) void k_moe(
        const float* __restrict__ x,  const float* __restrict__ Wg,
        const float* __restrict__ W1, const float* __restrict__ b1,
        const float* __restrict__ W2, const float* __restrict__ b2,
        float* __restrict__ out, float* __restrict__ w2s, float* __restrict__ v,
        float* __restrict__ c, float* __restrict__ s, int* __restrict__ ctr) {
    int lane = threadIdx.x & 63;
    int gw   = (blockIdx.x * NTHR + threadIdx.x) >> 6;   // global wave id 0..2047

    // ---- Phase A: w2s[row] = sum_d W2[row,d]  (one wave per row) ----
    {
        const float* p = W2 + (size_t)gw * D_;
        float acc = 0.f;
        #pragma unroll
        for (int k = 0; k < D_ / 256; ++k) {             // 8 float4 per lane
            float4 a = LD4(p + (lane + k * 64) * 4);
            acc += (a.x + a.y) + (a.z + a.w);
        }
        acc = waveReduceSum(acc);
        if (lane == 0) agentStore(&w2s[gw], acc);
    }
    gridBarrier(&ctr[0]);

    // ---- Phase B: v[row] = sum_h W1[row,h]*w2s[e,h]  (2 rows per wave) ----
    {
        #pragma unroll
        for (int r = 0; r < 2; ++r) {
            int row = 2 * gw + r;                        // 0..4095 = e*D_ + d
            int e   = row >> 11;
            const float* p = W1 + (size_t)row * H_;
            const float* w = w2s + e * H_;
            float acc = 0.f;
            #pragma unroll
            for (int k = 0; k < H_ / 256; ++k) {         // 4 float4 per lane
                float4 a = LD4(p + (lane + k * 64) * 4);
                float4 b = LD4(w + (lane + k * 64) * 4);
                acc += a.x * b.x + a.y * b.y + a.z * b.z + a.w * b.w;
            }
            acc = waveReduceSum(acc);
            if (lane == 0) agentStore(&v[row], acc);
        }
        if (blockIdx.x == NBLK - 1) {                    // c[e] = b1.w2s + sum(b2)
            __shared__ float lds[4];
            for (int e = 0; e < E_; ++e) {
                float acc = 0.f;
                for (int i = threadIdx.x; i < H_; i += NTHR) acc += b1[e * H_ + i] * w2s[e * H_ + i];
                for (int i = threadIdx.x; i < D_; i += NTHR) acc += b2[e * D_ + i];
                acc = waveReduceSum(acc);
                if (lane == 0) lds[threadIdx.x >> 6] = acc;
                __syncthreads();
                if (threadIdx.x == 0) agentStore(&c[e], lds[0] + lds[1] + lds[2] + lds[3]);
                __syncthreads();
            }
        }
    }
    gridBarrier(&ctr[1]);

    // ---- Phase C: one wave per token; gates + both expert dots in one x pass ----
    float cc0 = c[0], cc1 = c[1];
    {
        const float* xp = x + (size_t)gw * D_;
        float g0 = 0.f, g1 = 0.f, d0 = 0.f, d1 = 0.f;
        #pragma unroll
        for (int k = 0; k < D_ / 256; ++k) {
            int i = (lane + k * 64) * 4;
            float4 xv = LD4(xp + i);
            float4 v0 = LD4(v + i);
            float4 v1 = LD4(v + D_ + i);
            float4 wa = LD4(Wg + 2 * i);                 // Wg[d=i..i+1, e=0..1]
            float4 wb = LD4(Wg + 2 * i + 4);
            g0 += xv.x * wa.x + xv.y * wa.z + xv.z * wb.x + xv.w * wb.z;
            g1 += xv.x * wa.y + xv.y * wa.w + xv.z * wb.y + xv.w * wb.w;
            d0 += xv.x * v0.x + xv.y * v0.y + xv.z * v0.z + xv.w * v0.w;
            d1 += xv.x * v1.x + xv.y * v1.y + xv.z * v1.z + xv.w * v1.w;
        }
        #pragma unroll
        for (int o = 32; o > 0; o >>= 1) {
            g0 += __shfl_down(g0, o, 64);
            g1 += __shfl_down(g1, o, 64);
            d0 += __shfl_down(d0, o, 64);
            d1 += __shfl_down(d1, o, 64);
        }
        if (lane == 0) {
            int e = (g1 > g0) ? 1 : 0;                   // argmax, first index on tie
            float m  = fmaxf(g0, g1);
            float p0 = expf(g0 - m), p1 = expf(g1 - m);
            float gate = ((e == 0) ? p0 : p1) / (p0 + p1);
            float dot  = (e == 0) ? d0 : d1;
            agentStore(&s[gw], gate * (dot + ((e == 0) ? cc0 : cc1)));
        }
    }

    // ---- Tail: last-arriving block computes per-batch log_softmax over T ----
    __syncthreads();                                     // drains s stores (vmcnt 0)
    __shared__ int isLast;
    if (threadIdx.x == 0)
        isLast = (__hip_atomic_fetch_add(&ctr[2], 1, __ATOMIC_RELAXED,
                                         __HIP_MEMORY_SCOPE_AGENT) == NBLK - 1);
    __syncthreads();
    if (!isLast) return;

    int b = threadIdx.x >> 6;                            // wave -> batch (4 waves)
    const float* sb = s + b * T_;
    float vals[T_ / 64];
    float m = -INFINITY;
    #pragma unroll
    for (int k = 0; k < T_ / 64; ++k) {
        vals[k] = agentLoad(&sb[lane + k * 64]);         // sc1: coherent reads
        m = fmaxf(m, vals[k]);
    }
    #pragma unroll
    for (int o = 1; o < 64; o <<= 1) m = fmaxf(m, __shfl_xor(m, o, 64));
    float sum = 0.f;
    #pragma unroll
    for (int k = 0; k < T_ / 64; ++k) sum += expf(vals[k] - m);
    #pragma unroll
    for (int o = 1; o < 64; o <<= 1) sum += __shfl_xor(sum, o, 64);
    float lse = m + logf(sum);
    #pragma unroll
    for (int k = 0; k < T_ / 64; ++k) out[b * T_ + lane + k * 64] = vals[k] - lse;
}

extern "C" void kernel_launch(void* const* d_in, const int* in_sizes, int n_in,
                              void* d_out, int out_size, void* d_ws, size_t ws_size,
                              hipStream_t stream) {
    (void)in_sizes; (void)n_in; (void)out_size; (void)ws_size;
    const float* x  = (const float*)d_in[0];
    const float* Wg = (const float*)d_in[1];
    const float* W1 = (const float*)d_in[2];
    const float* b1 = (const float*)d_in[3];
    const float* W2 = (const float*)d_in[4];
    const float* b2 = (const float*)d_in[5];
    float* out = (float*)d_out;

    float* ws  = (float*)d_ws;
    float* w2s = ws;                    // [E,H]  2048 floats
    float* v   = ws + 2048;             // [E,D]  4096 floats
    float* c   = ws + 6144;             // [E]    2 floats
    int*   ctr = (int*)(ws + 6148);     // 3 ints (barrier0, barrier1, tail)
    float* s   = ws + 6160;             // [B,T]  2048 floats, 16B-aligned

    hipMemsetAsync((void*)ctr, 0, 3 * sizeof(int), stream);

    void* args[] = {(void*)&x, (void*)&Wg, (void*)&W1, (void*)&b1, (void*)&W2,
                    (void*)&b2, (void*)&out, (void*)&w2s, (void*)&v, (void*)&c,
                    (void*)&s, (void*)&ctr};
    hipLaunchCooperativeKernel((const void*)k_moe, dim3(NBLK), dim3(NTHR),
                               args, 0, stream);
}

// Round 5
// 30.680 us; speedup vs baseline: 2.4962x; 2.4962x over previous
//
#include <hip/hip_runtime.h>
#include <math.h>

#define B_ 4
#define T_ 512
#define D_ 2048
#define H_ 1024
#define E_ 2

#define LD4(p) (*reinterpret_cast<const float4*>(p))

__device__ __forceinline__ float waveReduceSum(float v) {
    #pragma unroll
    for (int o = 32; o > 0; o >>= 1) v += __shfl_down(v, o, 64);
    return v;
}

// Device-scope point ops (sc1 path). NO __threadfence anywhere (R2: wbl2/inv
// cache maintenance = 38us regression). NO spin loops (R4: spinner contention
// on the barrier line = ~20us/barrier).
__device__ __forceinline__ void agentStore(float* p, float v) {
    __hip_atomic_store(p, v, __ATOMIC_RELAXED, __HIP_MEMORY_SCOPE_AGENT);
}
__device__ __forceinline__ float agentLoad(const float* p) {
    return __hip_atomic_load(p, __ATOMIC_RELAXED, __HIP_MEMORY_SCOPE_AGENT);
}

// N1: w2s[row] = sum_d W2[row,d], row = e*H+h (2048 rows; one wave per row).
// Also zeroes the node-3 completion counter (consumed only in node 3).
__global__ __launch_bounds__(256) void k_w2sum(const float* __restrict__ W2,
                                               float* __restrict__ w2s,
                                               int* __restrict__ ctr) {
    if (blockIdx.x == 0 && threadIdx.x == 0) *ctr = 0;
    int gw   = (blockIdx.x * 256 + threadIdx.x) >> 6;   // 0..2047
    int lane = threadIdx.x & 63;
    const float* p = W2 + (size_t)gw * D_;
    float acc = 0.f;
    #pragma unroll
    for (int k = 0; k < D_ / 256; ++k) {                // 8 float4 per lane
        float4 a = LD4(p + (lane + k * 64) * 4);
        acc += (a.x + a.y) + (a.z + a.w);
    }
    acc = waveReduceSum(acc);
    if (lane == 0) w2s[gw] = acc;
}

// N2: v[e,d] = sum_h W1[e,d,h]*w2s[e,h]  (4096 rows; one wave per row).
// Blocks 1024/1025 compute c[e] = sum_h b1[e,h]*w2s[e,h] + sum_d b2[e,d].
__global__ __launch_bounds__(256) void k_vred(const float* __restrict__ W1,
                                              const float* __restrict__ w2s,
                                              const float* __restrict__ b1,
                                              const float* __restrict__ b2,
                                              float* __restrict__ v,
                                              float* __restrict__ c) {
    if (blockIdx.x >= 1024) {
        __shared__ float lds[4];
        int e = blockIdx.x - 1024;
        float acc = 0.f;
        for (int i = threadIdx.x; i < H_; i += 256) acc += b1[e * H_ + i] * w2s[e * H_ + i];
        for (int i = threadIdx.x; i < D_; i += 256) acc += b2[e * D_ + i];
        acc = waveReduceSum(acc);
        if ((threadIdx.x & 63) == 0) lds[threadIdx.x >> 6] = acc;
        __syncthreads();
        if (threadIdx.x == 0) c[e] = lds[0] + lds[1] + lds[2] + lds[3];
        return;
    }
    int row  = (blockIdx.x * 256 + threadIdx.x) >> 6;   // 0..4095 (= e*D_ + d)
    int lane = threadIdx.x & 63;
    int e    = row >> 11;                               // row / D_
    const float* p = W1 + (size_t)row * H_;
    const float* w = w2s + e * H_;
    float acc = 0.f;
    #pragma unroll
    for (int k = 0; k < H_ / 256; ++k) {                // 4 float4 per lane
        float4 a = LD4(p + (lane + k * 64) * 4);
        float4 b = LD4(w + (lane + k * 64) * 4);
        acc += a.x * b.x + a.y * b.y + a.z * b.z + a.w * b.w;
    }
    acc = waveReduceSum(acc);
    if (lane == 0) v[row] = acc;
}

// N3: one wave per token: gate logits + both expert dots in one x pass ->
// s[bt] = gate*(dot[idx]+c[idx]) via sc1 store. Last-arriving block (relaxed
// agent counter, no spin) computes the per-batch log_softmax and writes d_out.
__global__ __launch_bounds__(256) void k_token(const float* __restrict__ x,
                                               const float* __restrict__ Wg,
                                               const float* __restrict__ v,
                                               const float* __restrict__ c,
                                               float* __restrict__ s,
                                               float* __restrict__ out,
                                               int* __restrict__ ctr) {
    int lane = threadIdx.x & 63;
    int bt   = (blockIdx.x * 256 + threadIdx.x) >> 6;   // 0..2047
    const float* xp = x + (size_t)bt * D_;
    float g0 = 0.f, g1 = 0.f, d0 = 0.f, d1 = 0.f;
    #pragma unroll
    for (int k = 0; k < D_ / 256; ++k) {                // 8 iterations
        int i = (lane + k * 64) * 4;
        float4 xv = LD4(xp + i);
        float4 v0 = LD4(v + i);
        float4 v1 = LD4(v + D_ + i);
        float4 wa = LD4(Wg + 2 * i);                    // Wg[d=i..i+1, e=0..1]
        float4 wb = LD4(Wg + 2 * i + 4);
        g0 += xv.x * wa.x + xv.y * wa.z + xv.z * wb.x + xv.w * wb.z;
        g1 += xv.x * wa.y + xv.y * wa.w + xv.z * wb.y + xv.w * wb.w;
        d0 += xv.x * v0.x + xv.y * v0.y + xv.z * v0.z + xv.w * v0.w;
        d1 += xv.x * v1.x + xv.y * v1.y + xv.z * v1.z + xv.w * v1.w;
    }
    #pragma unroll
    for (int o = 32; o > 0; o >>= 1) {
        g0 += __shfl_down(g0, o, 64);
        g1 += __shfl_down(g1, o, 64);
        d0 += __shfl_down(d0, o, 64);
        d1 += __shfl_down(d1, o, 64);
    }
    if (lane == 0) {
        int e = (g1 > g0) ? 1 : 0;                      // argmax, first index on tie
        float m  = fmaxf(g0, g1);
        float p0 = expf(g0 - m), p1 = expf(g1 - m);
        float gate = ((e == 0) ? p0 : p1) / (p0 + p1);
        float dot  = (e == 0) ? d0 : d1;
        agentStore(&s[bt], gate * (dot + c[e]));        // sc1 write-through
    }

    __syncthreads();                                    // drains s stores (vmcnt 0)
    __shared__ int isLast;
    if (threadIdx.x == 0)
        isLast = (__hip_atomic_fetch_add(ctr, 1, __ATOMIC_RELAXED,
                                         __HIP_MEMORY_SCOPE_AGENT) ==
                  (int)gridDim.x - 1);
    __syncthreads();
    if (!isLast) return;                                // no spinning

    int b = threadIdx.x >> 6;                           // wave -> batch (4 waves)
    const float* sb = s + b * T_;
    float vals[T_ / 64];
    float m = -INFINITY;
    #pragma unroll
    for (int k = 0; k < T_ / 64; ++k) {                 // 8 per lane
        vals[k] = agentLoad(&sb[lane + k * 64]);        // sc1: coherent reads
        m = fmaxf(m, vals[k]);
    }
    #pragma unroll
    for (int o = 1; o < 64; o <<= 1) m = fmaxf(m, __shfl_xor(m, o, 64));
    float sum = 0.f;
    #pragma unroll
    for (int k = 0; k < T_ / 64; ++k) sum += expf(vals[k] - m);
    #pragma unroll
    for (int o = 1; o < 64; o <<= 1) sum += __shfl_xor(sum, o, 64);
    float lse = m + logf(sum);
    #pragma unroll
    for (int k = 0; k < T_ / 64; ++k) out[b * T_ + lane + k * 64] = vals[k] - lse;
}

extern "C" void kernel_launch(void* const* d_in, const int* in_sizes, int n_in,
                              void* d_out, int out_size, void* d_ws, size_t ws_size,
                              hipStream_t stream) {
    (void)in_sizes; (void)n_in; (void)out_size; (void)ws_size;
    const float* x  = (const float*)d_in[0];
    const float* Wg = (const float*)d_in[1];
    const float* W1 = (const float*)d_in[2];
    const float* b1 = (const float*)d_in[3];
    const float* W2 = (const float*)d_in[4];
    const float* b2 = (const float*)d_in[5];
    float* out = (float*)d_out;

    float* ws  = (float*)d_ws;
    float* w2s = ws;                    // [E,H]  2048 floats
    float* v   = ws + 2048;             // [E,D]  4096 floats
    float* c   = ws + 6144;             // [E]    2 floats
    int*   ctr = (int*)(ws + 6148);     // 1 int (node-3 tail counter)
    float* s   = ws + 6160;             // [B,T]  2048 floats, 16B-aligned

    k_w2sum<<<512,  256, 0, stream>>>(W2, w2s, ctr);
    k_vred <<<1026, 256, 0, stream>>>(W1, w2s, b1, b2, v, c);
    k_token<<<512,  256, 0, stream>>>(x, Wg, v, c, s, out, ctr);
}